// Round 16
// baseline (276.293 us; speedup 1.0000x reference)
//
#include <hip/hip_runtime.h>
#include <hip/hip_fp16.h>
#include <math.h>

#define N_NODES 100000
#define N_EDGES 1600000
#define N_GRAPHS 256
#define IN_DIM 128
#define F_SIZE 64
#define OUT_DIM 10

#define NB_BUCKETS 782   // bucket = dst >> 7  (128 nodes per bucket)
#define EPB 8192         // edges per partition block
#define NBLK_P 196       // ceil(E / EPB)
#define HIST_N (NB_BUCKETS * NBLK_P)      // 153272
#define SCAN_NB ((HIST_N + 1023) / 1024)  // 150

typedef _Float16 half8 __attribute__((ext_vector_type(8)));
typedef float f32x4 __attribute__((ext_vector_type(4)));

// ---------------- pass 1: per-(block,bucket) histogram via LDS atomics ----------------

__global__ __launch_bounds__(256) void k_hist(const int* __restrict__ dst,
                                              int* __restrict__ Hist, int e) {
    __shared__ int lh[NB_BUCKETS];
    const int tid = threadIdx.x;
    const int base = blockIdx.x * EPB;
    for (int i = tid; i < NB_BUCKETS; i += 256) lh[i] = 0;
    __syncthreads();
    if (base + EPB <= e) {
        const int4* d4 = (const int4*)(dst + base);
#pragma unroll
        for (int j = 0; j < 8; ++j) {
            const int4 a = d4[tid + 256 * j];
            atomicAdd(&lh[a.x >> 7], 1); atomicAdd(&lh[a.y >> 7], 1);
            atomicAdd(&lh[a.z >> 7], 1); atomicAdd(&lh[a.w >> 7], 1);
        }
    } else {
        for (int j = 0; j < 32; ++j) {
            const int i = base + tid * 32 + j;
            if (i < e) atomicAdd(&lh[dst[i] >> 7], 1);
        }
    }
    __syncthreads();
    for (int i = tid; i < NB_BUCKETS; i += 256) Hist[i * NBLK_P + blockIdx.x] = lh[i];
}

// ---------------- prefix scan (1024 elems / block), in-place capable ----------------

__global__ __launch_bounds__(256) void k_scan_local(const int* __restrict__ in,
                                                    int* __restrict__ outloc,
                                                    int* __restrict__ bsum, int n) {
    __shared__ int ts[256];
    const int tid = threadIdx.x;
    const int base = blockIdx.x * 1024 + tid * 4;
    int v0 = 0, v1 = 0, v2 = 0, v3 = 0;
    if (base + 3 < n) {
        v0 = in[base]; v1 = in[base + 1]; v2 = in[base + 2]; v3 = in[base + 3];
    } else {
        if (base + 0 < n) v0 = in[base];
        if (base + 1 < n) v1 = in[base + 1];
        if (base + 2 < n) v2 = in[base + 2];
    }
    const int s = v0 + v1 + v2 + v3;
    ts[tid] = s;
    __syncthreads();
    for (int off = 1; off < 256; off <<= 1) {
        int y = (tid >= off) ? ts[tid - off] : 0;
        __syncthreads();
        ts[tid] += y;
        __syncthreads();
    }
    const int incl = ts[tid];
    if (tid == 255) bsum[blockIdx.x] = incl;
    int run = incl - s;  // exclusive
    if (base < n)     outloc[base]     = run;
    run += v0;
    if (base + 1 < n) outloc[base + 1] = run;
    run += v1;
    if (base + 2 < n) outloc[base + 2] = run;
    run += v2;
    if (base + 3 < n) outloc[base + 3] = run;
}

// parallel exclusive scan of the per-block sums (nb <= 768)
__global__ __launch_bounds__(256) void k_scan_bsum_par(int* __restrict__ bsum, int nb) {
    __shared__ int ts[256];
    const int tid = threadIdx.x;
    int v[3];
    int s = 0;
    for (int j = 0; j < 3; ++j) {
        const int i = tid * 3 + j;
        v[j] = (i < nb) ? bsum[i] : 0;
        s += v[j];
    }
    ts[tid] = s;
    __syncthreads();
    for (int off = 1; off < 256; off <<= 1) {
        int y = (tid >= off) ? ts[tid - off] : 0;
        __syncthreads();
        ts[tid] += y;
        __syncthreads();
    }
    int run = ts[tid] - s;
    for (int j = 0; j < 3; ++j) {
        const int i = tid * 3 + j;
        if (i < nb) bsum[i] = run;
        run += v[j];
    }
}

// ------- pass 2: partition edges into bucket-contiguous regions (LDS-rank) -------
// part[pos] = { src | (dst&127)<<20 , bits(|w|) }

__global__ __launch_bounds__(256) void k_partition(const int* __restrict__ src,
                                                   const int* __restrict__ dst,
                                                   const float* __restrict__ ew,
                                                   const int* __restrict__ ScanS,
                                                   const int* __restrict__ bsum,
                                                   int2* __restrict__ part, int e) {
    __shared__ int sbase[NB_BUCKETS];
    __shared__ int lh[NB_BUCKETS];
    const int tid = threadIdx.x;
    const int k = blockIdx.x;
    const int base = k * EPB;
    for (int i = tid; i < NB_BUCKETS; i += 256) {
        const int idx = i * NBLK_P + k;
        sbase[i] = ScanS[idx] + bsum[idx >> 10];
        lh[i] = 0;
    }
    __syncthreads();
    if (base + EPB <= e) {
        const int4* d4 = (const int4*)(dst + base);
        const int4* s4 = (const int4*)(src + base);
        const float4* w4 = (const float4*)(ew + base);
        for (int j = 0; j < 8; ++j) {
            const int4 d = d4[tid + 256 * j];
            const int4 s = s4[tid + 256 * j];
            const float4 w = w4[tid + 256 * j];
            int b, r;
            b = d.x >> 7; r = atomicAdd(&lh[b], 1);
            part[sbase[b] + r] = make_int2(s.x | ((d.x & 127) << 20), __float_as_int(fabsf(w.x)));
            b = d.y >> 7; r = atomicAdd(&lh[b], 1);
            part[sbase[b] + r] = make_int2(s.y | ((d.y & 127) << 20), __float_as_int(fabsf(w.y)));
            b = d.z >> 7; r = atomicAdd(&lh[b], 1);
            part[sbase[b] + r] = make_int2(s.z | ((d.z & 127) << 20), __float_as_int(fabsf(w.z)));
            b = d.w >> 7; r = atomicAdd(&lh[b], 1);
            part[sbase[b] + r] = make_int2(s.w | ((d.w & 127) << 20), __float_as_int(fabsf(w.w)));
        }
    } else {
        for (int j = 0; j < 32; ++j) {
            const int i = base + tid * 32 + j;
            if (i < e) {
                const int d = dst[i];
                const int b = d >> 7;
                const int r = atomicAdd(&lh[b], 1);
                part[sbase[b] + r] =
                    make_int2(src[i] | ((d & 127) << 20), __float_as_int(fabsf(ew[i])));
            }
        }
    }
}

// ------- pass 3: per-bucket node-grouped CSR (EVEN-PADDED per node) + rowptr + dinv -------
// csr.x = BYTE offset of src row (src*128); pad entries {0, 0.0f} are exact no-ops.

__global__ __launch_bounds__(256) void k_bucket_csr(const int2* __restrict__ part,
                                                    const int* __restrict__ ScanS,
                                                    const int* __restrict__ bsum,
                                                    int2* __restrict__ csr,
                                                    int* __restrict__ rowptr,
                                                    float* __restrict__ dinv,
                                                    int e, int n) {
    __shared__ int cnt[128];
    __shared__ int basep[128];
    __shared__ int wofs[128];
    __shared__ float sw[128];
    const int b = blockIdx.x;
    const int tid = threadIdx.x;
    const int idx0 = b * NBLK_P;
    const int r0u = ScanS[idx0] + bsum[idx0 >> 10];
    int r1u;
    if (b == NB_BUCKETS - 1) {
        r1u = e;
    } else {
        const int idx1 = (b + 1) * NBLK_P;
        r1u = ScanS[idx1] + bsum[idx1 >> 10];
    }
    const int r0p = r0u + b * 128;           // padded csr base of this bucket
    const int r1p = r1u + (b + 1) * 128;     // next bucket's padded base

    if (tid < 128) { cnt[tid] = 0; wofs[tid] = 0; sw[tid] = 1.0f; }  // 1.0 = self-loop
    __syncthreads();
    for (int p = r0u + tid; p < r1u; p += 256) {
        atomicAdd(&cnt[(part[p].x >> 20) & 127], 1);
    }
    __syncthreads();
    if (tid < 128) basep[tid] = (cnt[tid] + 1) & ~1;   // padded count
    __syncthreads();
    for (int off = 1; off < 128; off <<= 1) {
        int y = 0;
        if (tid < 128 && tid >= off) y = basep[tid - off];
        __syncthreads();
        if (tid < 128) basep[tid] += y;   // inclusive scan of padded counts
        __syncthreads();
    }
    if (tid < 128) {
        const int node = (b << 7) + tid;
        const int pc = (cnt[tid] + 1) & ~1;
        if (node <= n) rowptr[node] = r0p + basep[tid] - pc;
    }
    __syncthreads();
    for (int p = r0u + tid; p < r1u; p += 256) {
        const int2 pe = part[p];
        const int dl = (pe.x >> 20) & 127;
        const int rr = atomicAdd(&wofs[dl], 1);
        atomicAdd(&sw[dl], __int_as_float(pe.y));
        const int pc = (cnt[dl] + 1) & ~1;
        csr[r0p + basep[dl] - pc + rr] = make_int2((pe.x & 0xFFFFF) << 7, pe.y);
    }
    __syncthreads();
    if (tid < 128) {
        if (cnt[tid] & 1) {
            csr[r0p + basep[tid] - 1] = make_int2(0, 0);
        }
        const int node = (b << 7) + tid;
        if (node < n) {
            const float s = sw[tid];
            dinv[node] = (s > 0.f) ? (1.0f / sqrtf(s)) : 0.f;
        }
    }
    // zero-fill gap to next bucket's base (last node of bucket reads into it)
    const int gstart = r0p + basep[127];
    for (int q = gstart + tid; q < r1p; q += 256) csr[q] = make_int2(0, 0);
}

// ------- MFMA GEMM: Hs[n][64] = fp16( dinv * (X[n][K] @ W[K][64]) ) -------

template <int K, bool F32IN>
__global__ __launch_bounds__(256) void k_gemm_mfma(const void* __restrict__ Xv,
                                                   const float* __restrict__ W,
                                                   const float* __restrict__ dinv,
                                                   __half* __restrict__ Hs, int n) {
    constexpr int KP = K + 8;
    __shared__ _Float16 Xs[64 * KP];
    __shared__ _Float16 Wt[64 * KP];
    __shared__ _Float16 Ct[64 * 72];
    const int tid = threadIdx.x;
    const int row0 = blockIdx.x * 64;

    if (F32IN) {
        const float* X = (const float*)Xv;
        for (int idx = tid; idx < 64 * (K / 4); idx += 256) {
            const int r = idx / (K / 4);
            const int c4 = idx % (K / 4);
            float4 v = make_float4(0.f, 0.f, 0.f, 0.f);
            if (row0 + r < n) v = ((const float4*)(X + (size_t)(row0 + r) * K))[c4];
            union { uint2 u; __half2 h[2]; } pk;
            pk.h[0] = __floats2half2_rn(v.x, v.y);
            pk.h[1] = __floats2half2_rn(v.z, v.w);
            *(uint2*)&Xs[r * KP + c4 * 4] = pk.u;
        }
    } else {
        const __half* X = (const __half*)Xv;
        for (int idx = tid; idx < 64 * (K / 4); idx += 256) {
            const int r = idx / (K / 4);
            const int c4 = idx % (K / 4);
            uint2 v = make_uint2(0u, 0u);
            if (row0 + r < n) v = *(const uint2*)(X + (size_t)(row0 + r) * K + c4 * 4);
            *(uint2*)&Xs[r * KP + c4 * 4] = v;
        }
    }
    for (int idx = tid; idx < K * 16; idx += 256) {
        const int k = idx >> 4;
        const int c4 = idx & 15;
        const float4 w = ((const float4*)W)[idx];
        Wt[(c4 * 4 + 0) * KP + k] = (_Float16)w.x;
        Wt[(c4 * 4 + 1) * KP + k] = (_Float16)w.y;
        Wt[(c4 * 4 + 2) * KP + k] = (_Float16)w.z;
        Wt[(c4 * 4 + 3) * KP + k] = (_Float16)w.w;
    }
    __syncthreads();

    const int wv = tid >> 6;
    const int lane = tid & 63;
    const int lr = lane & 15;
    const int lg = lane >> 4;

    f32x4 acc[4] = {};
    const _Float16* xrow = &Xs[(wv * 16 + lr) * KP + lg * 8];
#pragma unroll
    for (int s = 0; s < K / 32; ++s) {
        const half8 a = *(const half8*)(xrow + s * 32);
#pragma unroll
        for (int c = 0; c < 4; ++c) {
            const half8 b = *(const half8*)&Wt[(c * 16 + lr) * KP + s * 32 + lg * 8];
            acc[c] = __builtin_amdgcn_mfma_f32_16x16x32_f16(a, b, acc[c], 0, 0, 0);
        }
    }

    const int lrow = wv * 16 + lg * 4;
    const int grow = row0 + lrow;
    float4 dv = make_float4(0.f, 0.f, 0.f, 0.f);
    if (grow < n) dv = *(const float4*)&dinv[grow];
    const float dvr[4] = {dv.x, dv.y, dv.z, dv.w};
#pragma unroll
    for (int c = 0; c < 4; ++c) {
#pragma unroll
        for (int r = 0; r < 4; ++r) {
            Ct[(lrow + r) * 72 + c * 16 + lr] = (_Float16)(acc[c][r] * dvr[r]);
        }
    }
    __syncthreads();
    for (int idx = tid; idx < 64 * 16; idx += 256) {
        const int r = idx >> 4;
        const int u = idx & 15;
        if (row0 + r < n) {
            *(uint2*)(Hs + (size_t)(row0 + r) * 64 + u * 4) =
                *(const uint2*)&Ct[r * 72 + u * 4];
        }
    }
}

// ------- aggregate: out(fp16) = relu(dinv[d]*(sum_in w*Hs[src] + Hs[d]) + b) -------
// 1 wave per dst node; lane = (edge-slot e8 = lane>>3) x (feat-octet f8 = lane&7).
// R13 form: two INDEPENDENT csr int2 loads + two independent 16B gathers per iter
// (independent-request count beats instruction count — R14 pair-load regressed).
// csr.x = src row BYTE offset. Pad entries {0,0} are exact no-ops.

#define AGG_EDGE8(cE)                                                           \
    {                                                                           \
        union { uint4 u; __half2 h2[4]; } hv;                                   \
        hv.u = *(const uint4*)(hsb + (size_t)(unsigned)(cE).x + (f8 << 4));     \
        const float wE = __int_as_float((cE).y);                                \
        const float2 q0 = __half22float2(hv.h2[0]);                             \
        const float2 q1 = __half22float2(hv.h2[1]);                             \
        const float2 q2 = __half22float2(hv.h2[2]);                             \
        const float2 q3 = __half22float2(hv.h2[3]);                             \
        a0.x = fmaf(wE, q0.x, a0.x);                                            \
        a0.y = fmaf(wE, q0.y, a0.y);                                            \
        a0.z = fmaf(wE, q1.x, a0.z);                                            \
        a0.w = fmaf(wE, q1.y, a0.w);                                            \
        a1.x = fmaf(wE, q2.x, a1.x);                                            \
        a1.y = fmaf(wE, q2.y, a1.y);                                            \
        a1.z = fmaf(wE, q3.x, a1.z);                                            \
        a1.w = fmaf(wE, q3.y, a1.w);                                            \
    }

__global__ __launch_bounds__(256) void k_agg(const __half* __restrict__ Hs,
                                             const int* __restrict__ rowptr,
                                             const int2* __restrict__ csr,
                                             const float* __restrict__ dinv,
                                             const float* __restrict__ b,
                                             __half* __restrict__ out) {
    const int node = blockIdx.x * 4 + (threadIdx.x >> 6);
    const int lane = threadIdx.x & 63;
    const int e8 = lane >> 3;
    const int f8 = lane & 7;
    const char* hsb = (const char*)Hs;

    const int p0 = rowptr[node];
    const int p1 = rowptr[node + 1];

    float4 a0 = make_float4(0.f, 0.f, 0.f, 0.f);
    float4 a1 = make_float4(0.f, 0.f, 0.f, 0.f);
    int p = p0 + e8;
    for (; p + 8 < p1; p += 16) {
        const int2 c0 = csr[p];
        const int2 c1 = csr[p + 8];
        AGG_EDGE8(c0); AGG_EDGE8(c1);
    }
    if (p < p1) {
        const int2 c0 = csr[p];
        AGG_EDGE8(c0);
    }

#pragma unroll
    for (int m = 8; m < 64; m <<= 1) {
        a0.x += __shfl_xor(a0.x, m, 64);
        a0.y += __shfl_xor(a0.y, m, 64);
        a0.z += __shfl_xor(a0.z, m, 64);
        a0.w += __shfl_xor(a0.w, m, 64);
        a1.x += __shfl_xor(a1.x, m, 64);
        a1.y += __shfl_xor(a1.y, m, 64);
        a1.z += __shfl_xor(a1.z, m, 64);
        a1.w += __shfl_xor(a1.w, m, 64);
    }

    if (e8 == 0) {
        union { uint4 u; __half2 h2[4]; } hs;
        hs.u = *(const uint4*)(hsb + ((size_t)node << 7) + (f8 << 4));
        const float2 s0 = __half22float2(hs.h2[0]);
        const float2 s1 = __half22float2(hs.h2[1]);
        const float2 s2 = __half22float2(hs.h2[2]);
        const float2 s3 = __half22float2(hs.h2[3]);
        const float di = dinv[node];
        const float4 b0 = *(const float4*)&b[f8 << 3];
        const float4 b1 = *(const float4*)&b[(f8 << 3) + 4];
        union { uint4 u; __half2 h2[4]; } ov;
        ov.h2[0] = __floats2half2_rn(fmaxf(fmaf(di, a0.x + s0.x, b0.x), 0.f),
                                     fmaxf(fmaf(di, a0.y + s0.y, b0.y), 0.f));
        ov.h2[1] = __floats2half2_rn(fmaxf(fmaf(di, a0.z + s1.x, b0.z), 0.f),
                                     fmaxf(fmaf(di, a0.w + s1.y, b0.w), 0.f));
        ov.h2[2] = __floats2half2_rn(fmaxf(fmaf(di, a1.x + s2.x, b1.x), 0.f),
                                     fmaxf(fmaf(di, a1.y + s2.y, b1.y), 0.f));
        ov.h2[3] = __floats2half2_rn(fmaxf(fmaf(di, a1.z + s3.x, b1.z), 0.f),
                                     fmaxf(fmaf(di, a1.w + s3.y, b1.w), 0.f));
        *(uint4*)((char*)out + ((size_t)node << 7) + (f8 << 4)) = ov.u;
    }
}

// ------- fused readout: pooled = mean((A+B+C)/3) per graph; logits; softmax -------

__device__ __forceinline__ int lower_bound_i(const int* __restrict__ a, int n, int v) {
    int lo = 0, hi = n;
    while (lo < hi) {
        int mid = (lo + hi) >> 1;
        if (a[mid] < v) lo = mid + 1; else hi = mid;
    }
    return lo;
}

__global__ __launch_bounds__(256) void k_pool3_head(const __half* __restrict__ A,
                                                    const __half* __restrict__ B,
                                                    const __half* __restrict__ C,
                                                    const int* __restrict__ batch,
                                                    const float* __restrict__ Wl,
                                                    const float* __restrict__ bl,
                                                    float* __restrict__ out, int n) {
    const int g = blockIdx.x;
    const int tid = threadIdx.x;
    const int start = lower_bound_i(batch, n, g);
    const int end = lower_bound_i(batch, n, g + 1);

    const int fq = tid & 15;
    const int q = tid >> 4;
    float4 s = make_float4(0.f, 0.f, 0.f, 0.f);
    for (int nn = start + q; nn < end; nn += 16) {
        const size_t base = (size_t)nn * 64 + fq * 4;
        union { uint2 u; __half2 h2[2]; } va, vb, vc;
        va.u = *(const uint2*)&A[base];
        vb.u = *(const uint2*)&B[base];
        vc.u = *(const uint2*)&C[base];
        const float2 a0 = __half22float2(va.h2[0]);
        const float2 a1 = __half22float2(va.h2[1]);
        const float2 b0 = __half22float2(vb.h2[0]);
        const float2 b1 = __half22float2(vb.h2[1]);
        const float2 c0 = __half22float2(vc.h2[0]);
        const float2 c1 = __half22float2(vc.h2[1]);
        s.x += a0.x + b0.x + c0.x;
        s.y += a0.y + b0.y + c0.y;
        s.z += a1.x + b1.x + c1.x;
        s.w += a1.y + b1.y + c1.y;
    }
    __shared__ float4 red[16][16];
    red[q][fq] = s;
    __syncthreads();
    for (int off = 8; off > 0; off >>= 1) {
        if (q < off) {
            float4 a = red[q][fq];
            const float4 bb = red[q + off][fq];
            a.x += bb.x; a.y += bb.y; a.z += bb.z; a.w += bb.w;
            red[q][fq] = a;
        }
        __syncthreads();
    }
    __shared__ float pool[64];
    __shared__ float logits[10];
    if (tid < 16) {
        const float4 t = red[0][fq];
        pool[fq * 4 + 0] = t.x;
        pool[fq * 4 + 1] = t.y;
        pool[fq * 4 + 2] = t.z;
        pool[fq * 4 + 3] = t.w;
    }
    __syncthreads();
    const int cnt = end - start;
    const float scale = 1.0f / (3.0f * (float)(cnt < 1 ? 1 : cnt));
    if (tid < 10) {
        float acc = bl[tid];
        for (int k = 0; k < 64; ++k) {
            acc = fmaf(pool[k] * scale, Wl[k * 10 + tid], acc);
        }
        logits[tid] = acc;
    }
    __syncthreads();
    if (tid == 0) {
        float m = logits[0];
#pragma unroll
        for (int j = 1; j < 10; ++j) m = fmaxf(m, logits[j]);
        float sum = 0.f;
        float ex[10];
#pragma unroll
        for (int j = 0; j < 10; ++j) { ex[j] = expf(logits[j] - m); sum += ex[j]; }
        const float inv = 1.f / sum;
#pragma unroll
        for (int j = 0; j < 10; ++j) out[g * 10 + j] = ex[j] * inv;
    }
}

// ---------------- launcher ----------------

static inline size_t align256(size_t x) { return (x + 255) & ~(size_t)255; }

extern "C" void kernel_launch(void* const* d_in, const int* in_sizes, int n_in,
                              void* d_out, int out_size, void* d_ws, size_t ws_size,
                              hipStream_t stream) {
    const float* x  = (const float*)d_in[0];
    const float* ew = (const float*)d_in[1];
    const float* W1 = (const float*)d_in[2];
    const float* b1 = (const float*)d_in[3];
    const float* W2 = (const float*)d_in[4];
    const float* b2 = (const float*)d_in[5];
    const float* W3 = (const float*)d_in[6];
    const float* b3 = (const float*)d_in[7];
    const float* Wl = (const float*)d_in[8];
    const float* bl = (const float*)d_in[9];
    const int* eidx  = (const int*)d_in[10];
    const int* batch = (const int*)d_in[11];
    const int* src = eidx;
    const int* dst = eidx + N_EDGES;

    const size_t CSR_CAP = (size_t)N_EDGES + NB_BUCKETS * 128 + 256;

    // workspace layout — every region 256B-aligned (Hs row gathers need 128B alignment!)
    char* base = (char*)d_ws;
    size_t off = 0;
    float* dinv   = (float*)(base + off); off = align256(off + N_NODES * 4);
    int* rowptr   = (int*)(base + off);   off = align256(off + (N_NODES + 1) * 4);
    int* Hist     = (int*)(base + off);   off = align256(off + HIST_N * 4);
    int* bsum     = (int*)(base + off);   off = align256(off + 640 * 4);
    int2* part    = (int2*)(base + off);  off = align256(off + (size_t)N_EDGES * 8);
    int2* csr     = (int2*)(base + off);  off = align256(off + CSR_CAP * 8);
    __half* Hs    = (__half*)(base + off); off = align256(off + (size_t)64 * N_NODES * 2);
    __half* A     = (__half*)(base + off); off = align256(off + (size_t)64 * N_NODES * 2);
    __half* B     = (__half*)(base + off); off = align256(off + (size_t)64 * N_NODES * 2);
    __half* C     = (__half*)(base + off); off = align256(off + (size_t)64 * N_NODES * 2);

    float* outf = (float*)d_out;

    // ---- atomic-free CSR build (counting sort, even-padded rows) ----
    k_hist<<<NBLK_P, 256, 0, stream>>>(dst, Hist, N_EDGES);
    k_scan_local<<<SCAN_NB, 256, 0, stream>>>(Hist, Hist, bsum, HIST_N);
    k_scan_bsum_par<<<1, 256, 0, stream>>>(bsum, SCAN_NB);
    k_partition<<<NBLK_P, 256, 0, stream>>>(src, dst, ew, Hist, bsum, part, N_EDGES);
    k_bucket_csr<<<NB_BUCKETS, 256, 0, stream>>>(part, Hist, bsum, csr, rowptr, dinv,
                                                 N_EDGES, N_NODES);

    const int nagg = N_NODES / 4;              // 25000 blocks, 1 wave per node
    const int ngemm = (N_NODES + 63) / 64;     // 1563 blocks

    // layer 1
    k_gemm_mfma<128, true><<<ngemm, 256, 0, stream>>>(x, W1, dinv, Hs, N_NODES);
    k_agg<<<nagg, 256, 0, stream>>>(Hs, rowptr, csr, dinv, b1, A);
    // layer 2
    k_gemm_mfma<64, false><<<ngemm, 256, 0, stream>>>(A, W2, dinv, Hs, N_NODES);
    k_agg<<<nagg, 256, 0, stream>>>(Hs, rowptr, csr, dinv, b2, B);
    // layer 3
    k_gemm_mfma<64, false><<<ngemm, 256, 0, stream>>>(B, W3, dinv, Hs, N_NODES);
    k_agg<<<nagg, 256, 0, stream>>>(Hs, rowptr, csr, dinv, b3, C);

    // fused readout (3-buffer pool + head + softmax)
    k_pool3_head<<<N_GRAPHS, 256, 0, stream>>>(A, B, C, batch, Wl, bl, outf, N_NODES);
}

// Round 17
// 249.242 us; speedup vs baseline: 1.1085x; 1.1085x over previous
//
#include <hip/hip_runtime.h>
#include <hip/hip_fp16.h>
#include <math.h>

#define N_NODES 100000
#define N_EDGES 1600000
#define N_GRAPHS 256
#define IN_DIM 128
#define F_SIZE 64
#define OUT_DIM 10

#define NB_BUCKETS 782   // bucket = dst >> 7  (128 nodes per bucket)
#define EPB 8192         // edges per partition block
#define NBLK_P 196       // ceil(E / EPB)
#define HIST_N (NB_BUCKETS * NBLK_P)      // 153272
#define SCAN_NB ((HIST_N + 1023) / 1024)  // 150

typedef _Float16 half8 __attribute__((ext_vector_type(8)));
typedef float f32x4 __attribute__((ext_vector_type(4)));

// ---------------- pass 1: per-(block,bucket) histogram via LDS atomics ----------------

__global__ __launch_bounds__(256) void k_hist(const int* __restrict__ dst,
                                              int* __restrict__ Hist, int e) {
    __shared__ int lh[NB_BUCKETS];
    const int tid = threadIdx.x;
    const int base = blockIdx.x * EPB;
    for (int i = tid; i < NB_BUCKETS; i += 256) lh[i] = 0;
    __syncthreads();
    if (base + EPB <= e) {
        const int4* d4 = (const int4*)(dst + base);
#pragma unroll
        for (int j = 0; j < 8; ++j) {
            const int4 a = d4[tid + 256 * j];
            atomicAdd(&lh[a.x >> 7], 1); atomicAdd(&lh[a.y >> 7], 1);
            atomicAdd(&lh[a.z >> 7], 1); atomicAdd(&lh[a.w >> 7], 1);
        }
    } else {
        for (int j = 0; j < 32; ++j) {
            const int i = base + tid * 32 + j;
            if (i < e) atomicAdd(&lh[dst[i] >> 7], 1);
        }
    }
    __syncthreads();
    for (int i = tid; i < NB_BUCKETS; i += 256) Hist[i * NBLK_P + blockIdx.x] = lh[i];
}

// ---------------- prefix scan (1024 elems / block), in-place capable ----------------

__global__ __launch_bounds__(256) void k_scan_local(const int* __restrict__ in,
                                                    int* __restrict__ outloc,
                                                    int* __restrict__ bsum, int n) {
    __shared__ int ts[256];
    const int tid = threadIdx.x;
    const int base = blockIdx.x * 1024 + tid * 4;
    int v0 = 0, v1 = 0, v2 = 0, v3 = 0;
    if (base + 3 < n) {
        v0 = in[base]; v1 = in[base + 1]; v2 = in[base + 2]; v3 = in[base + 3];
    } else {
        if (base + 0 < n) v0 = in[base];
        if (base + 1 < n) v1 = in[base + 1];
        if (base + 2 < n) v2 = in[base + 2];
    }
    const int s = v0 + v1 + v2 + v3;
    ts[tid] = s;
    __syncthreads();
    for (int off = 1; off < 256; off <<= 1) {
        int y = (tid >= off) ? ts[tid - off] : 0;
        __syncthreads();
        ts[tid] += y;
        __syncthreads();
    }
    const int incl = ts[tid];
    if (tid == 255) bsum[blockIdx.x] = incl;
    int run = incl - s;  // exclusive
    if (base < n)     outloc[base]     = run;
    run += v0;
    if (base + 1 < n) outloc[base + 1] = run;
    run += v1;
    if (base + 2 < n) outloc[base + 2] = run;
    run += v2;
    if (base + 3 < n) outloc[base + 3] = run;
}

// parallel exclusive scan of the per-block sums (nb <= 768)
__global__ __launch_bounds__(256) void k_scan_bsum_par(int* __restrict__ bsum, int nb) {
    __shared__ int ts[256];
    const int tid = threadIdx.x;
    int v[3];
    int s = 0;
    for (int j = 0; j < 3; ++j) {
        const int i = tid * 3 + j;
        v[j] = (i < nb) ? bsum[i] : 0;
        s += v[j];
    }
    ts[tid] = s;
    __syncthreads();
    for (int off = 1; off < 256; off <<= 1) {
        int y = (tid >= off) ? ts[tid - off] : 0;
        __syncthreads();
        ts[tid] += y;
        __syncthreads();
    }
    int run = ts[tid] - s;
    for (int j = 0; j < 3; ++j) {
        const int i = tid * 3 + j;
        if (i < nb) bsum[i] = run;
        run += v[j];
    }
}

// ------- pass 2: partition edges into bucket-contiguous regions (LDS-rank) -------
// part[pos] = { src | (dst&127)<<20 , bits(|w|) }

__global__ __launch_bounds__(256) void k_partition(const int* __restrict__ src,
                                                   const int* __restrict__ dst,
                                                   const float* __restrict__ ew,
                                                   const int* __restrict__ ScanS,
                                                   const int* __restrict__ bsum,
                                                   int2* __restrict__ part, int e) {
    __shared__ int sbase[NB_BUCKETS];
    __shared__ int lh[NB_BUCKETS];
    const int tid = threadIdx.x;
    const int k = blockIdx.x;
    const int base = k * EPB;
    for (int i = tid; i < NB_BUCKETS; i += 256) {
        const int idx = i * NBLK_P + k;
        sbase[i] = ScanS[idx] + bsum[idx >> 10];
        lh[i] = 0;
    }
    __syncthreads();
    if (base + EPB <= e) {
        const int4* d4 = (const int4*)(dst + base);
        const int4* s4 = (const int4*)(src + base);
        const float4* w4 = (const float4*)(ew + base);
        for (int j = 0; j < 8; ++j) {
            const int4 d = d4[tid + 256 * j];
            const int4 s = s4[tid + 256 * j];
            const float4 w = w4[tid + 256 * j];
            int b, r;
            b = d.x >> 7; r = atomicAdd(&lh[b], 1);
            part[sbase[b] + r] = make_int2(s.x | ((d.x & 127) << 20), __float_as_int(fabsf(w.x)));
            b = d.y >> 7; r = atomicAdd(&lh[b], 1);
            part[sbase[b] + r] = make_int2(s.y | ((d.y & 127) << 20), __float_as_int(fabsf(w.y)));
            b = d.z >> 7; r = atomicAdd(&lh[b], 1);
            part[sbase[b] + r] = make_int2(s.z | ((d.z & 127) << 20), __float_as_int(fabsf(w.z)));
            b = d.w >> 7; r = atomicAdd(&lh[b], 1);
            part[sbase[b] + r] = make_int2(s.w | ((d.w & 127) << 20), __float_as_int(fabsf(w.w)));
        }
    } else {
        for (int j = 0; j < 32; ++j) {
            const int i = base + tid * 32 + j;
            if (i < e) {
                const int d = dst[i];
                const int b = d >> 7;
                const int r = atomicAdd(&lh[b], 1);
                part[sbase[b] + r] =
                    make_int2(src[i] | ((d & 127) << 20), __float_as_int(fabsf(ew[i])));
            }
        }
    }
}

// ------- pass 3: per-bucket node-grouped CSR + rowptr + fused weighted degree -> dinv -------
// UNPADDED (exact R13 build — padding correlated with the R14/R15 agg regressions).
// csr.x = BYTE offset of src row (src*128).

__global__ __launch_bounds__(256) void k_bucket_csr(const int2* __restrict__ part,
                                                    const int* __restrict__ ScanS,
                                                    const int* __restrict__ bsum,
                                                    int2* __restrict__ csr,
                                                    int* __restrict__ rowptr,
                                                    float* __restrict__ dinv,
                                                    int e, int n) {
    __shared__ int cnt[128];
    __shared__ int basep[128];
    __shared__ int wofs[128];
    __shared__ float sw[128];
    const int b = blockIdx.x;
    const int tid = threadIdx.x;
    const int idx0 = b * NBLK_P;
    const int r0 = ScanS[idx0] + bsum[idx0 >> 10];
    int r1;
    if (b == NB_BUCKETS - 1) {
        r1 = e;
    } else {
        const int idx1 = (b + 1) * NBLK_P;
        r1 = ScanS[idx1] + bsum[idx1 >> 10];
    }
    if (tid < 128) { cnt[tid] = 0; wofs[tid] = 0; sw[tid] = 1.0f; }  // 1.0 = self-loop
    __syncthreads();
    for (int p = r0 + tid; p < r1; p += 256) {
        atomicAdd(&cnt[(part[p].x >> 20) & 127], 1);
    }
    __syncthreads();
    if (tid < 128) basep[tid] = cnt[tid];
    __syncthreads();
    for (int off = 1; off < 128; off <<= 1) {
        int y = 0;
        if (tid < 128 && tid >= off) y = basep[tid - off];
        __syncthreads();
        if (tid < 128) basep[tid] += y;
        __syncthreads();
    }
    if (tid < 128) {
        const int node = (b << 7) + tid;
        if (node < n) rowptr[node] = r0 + basep[tid] - cnt[tid];
    }
    if (b == NB_BUCKETS - 1 && tid == 0) rowptr[n] = e;
    __syncthreads();
    for (int p = r0 + tid; p < r1; p += 256) {
        const int2 pe = part[p];
        const int dl = (pe.x >> 20) & 127;
        const int rr = atomicAdd(&wofs[dl], 1);
        atomicAdd(&sw[dl], __int_as_float(pe.y));
        csr[r0 + basep[dl] - cnt[dl] + rr] = make_int2((pe.x & 0xFFFFF) << 7, pe.y);
    }
    __syncthreads();
    if (tid < 128) {
        const int node = (b << 7) + tid;
        if (node < n) {
            const float s = sw[tid];
            dinv[node] = (s > 0.f) ? (1.0f / sqrtf(s)) : 0.f;
        }
    }
}

// ------- MFMA GEMM: Hs[n][64] = fp16( dinv * (X[n][K] @ W[K][64]) ) -------

template <int K, bool F32IN>
__global__ __launch_bounds__(256) void k_gemm_mfma(const void* __restrict__ Xv,
                                                   const float* __restrict__ W,
                                                   const float* __restrict__ dinv,
                                                   __half* __restrict__ Hs, int n) {
    constexpr int KP = K + 8;
    __shared__ _Float16 Xs[64 * KP];
    __shared__ _Float16 Wt[64 * KP];
    __shared__ _Float16 Ct[64 * 72];
    const int tid = threadIdx.x;
    const int row0 = blockIdx.x * 64;

    if (F32IN) {
        const float* X = (const float*)Xv;
        for (int idx = tid; idx < 64 * (K / 4); idx += 256) {
            const int r = idx / (K / 4);
            const int c4 = idx % (K / 4);
            float4 v = make_float4(0.f, 0.f, 0.f, 0.f);
            if (row0 + r < n) v = ((const float4*)(X + (size_t)(row0 + r) * K))[c4];
            union { uint2 u; __half2 h[2]; } pk;
            pk.h[0] = __floats2half2_rn(v.x, v.y);
            pk.h[1] = __floats2half2_rn(v.z, v.w);
            *(uint2*)&Xs[r * KP + c4 * 4] = pk.u;
        }
    } else {
        const __half* X = (const __half*)Xv;
        for (int idx = tid; idx < 64 * (K / 4); idx += 256) {
            const int r = idx / (K / 4);
            const int c4 = idx % (K / 4);
            uint2 v = make_uint2(0u, 0u);
            if (row0 + r < n) v = *(const uint2*)(X + (size_t)(row0 + r) * K + c4 * 4);
            *(uint2*)&Xs[r * KP + c4 * 4] = v;
        }
    }
    for (int idx = tid; idx < K * 16; idx += 256) {
        const int k = idx >> 4;
        const int c4 = idx & 15;
        const float4 w = ((const float4*)W)[idx];
        Wt[(c4 * 4 + 0) * KP + k] = (_Float16)w.x;
        Wt[(c4 * 4 + 1) * KP + k] = (_Float16)w.y;
        Wt[(c4 * 4 + 2) * KP + k] = (_Float16)w.z;
        Wt[(c4 * 4 + 3) * KP + k] = (_Float16)w.w;
    }
    __syncthreads();

    const int wv = tid >> 6;
    const int lane = tid & 63;
    const int lr = lane & 15;
    const int lg = lane >> 4;

    f32x4 acc[4] = {};
    const _Float16* xrow = &Xs[(wv * 16 + lr) * KP + lg * 8];
#pragma unroll
    for (int s = 0; s < K / 32; ++s) {
        const half8 a = *(const half8*)(xrow + s * 32);
#pragma unroll
        for (int c = 0; c < 4; ++c) {
            const half8 b = *(const half8*)&Wt[(c * 16 + lr) * KP + s * 32 + lg * 8];
            acc[c] = __builtin_amdgcn_mfma_f32_16x16x32_f16(a, b, acc[c], 0, 0, 0);
        }
    }

    const int lrow = wv * 16 + lg * 4;
    const int grow = row0 + lrow;
    float4 dv = make_float4(0.f, 0.f, 0.f, 0.f);
    if (grow < n) dv = *(const float4*)&dinv[grow];
    const float dvr[4] = {dv.x, dv.y, dv.z, dv.w};
#pragma unroll
    for (int c = 0; c < 4; ++c) {
#pragma unroll
        for (int r = 0; r < 4; ++r) {
            Ct[(lrow + r) * 72 + c * 16 + lr] = (_Float16)(acc[c][r] * dvr[r]);
        }
    }
    __syncthreads();
    for (int idx = tid; idx < 64 * 16; idx += 256) {
        const int r = idx >> 4;
        const int u = idx & 15;
        if (row0 + r < n) {
            *(uint2*)(Hs + (size_t)(row0 + r) * 64 + u * 4) =
                *(const uint2*)&Ct[r * 72 + u * 4];
        }
    }
}

// ------- aggregate: out(fp16) = relu(dinv[d]*(sum_in w*Hs[src] + Hs[d]) + b) -------
// 1 wave per dst node; lane = (edge-slot e8 = lane>>3) x (feat-octet f8 = lane&7).
// Two INDEPENDENT csr int2 loads + two independent 16B gathers per iter + tail.
// csr.x = src row BYTE offset.

#define AGG_EDGE8(cE)                                                           \
    {                                                                           \
        union { uint4 u; __half2 h2[4]; } hv;                                   \
        hv.u = *(const uint4*)(hsb + (size_t)(unsigned)(cE).x + (f8 << 4));     \
        const float wE = __int_as_float((cE).y);                                \
        const float2 q0 = __half22float2(hv.h2[0]);                             \
        const float2 q1 = __half22float2(hv.h2[1]);                             \
        const float2 q2 = __half22float2(hv.h2[2]);                             \
        const float2 q3 = __half22float2(hv.h2[3]);                             \
        a0.x = fmaf(wE, q0.x, a0.x);                                            \
        a0.y = fmaf(wE, q0.y, a0.y);                                            \
        a0.z = fmaf(wE, q1.x, a0.z);                                            \
        a0.w = fmaf(wE, q1.y, a0.w);                                            \
        a1.x = fmaf(wE, q2.x, a1.x);                                            \
        a1.y = fmaf(wE, q2.y, a1.y);                                            \
        a1.z = fmaf(wE, q3.x, a1.z);                                            \
        a1.w = fmaf(wE, q3.y, a1.w);                                            \
    }

__global__ __launch_bounds__(256) void k_agg(const __half* __restrict__ Hs,
                                             const int* __restrict__ rowptr,
                                             const int2* __restrict__ csr,
                                             const float* __restrict__ dinv,
                                             const float* __restrict__ b,
                                             __half* __restrict__ out) {
    const int node = blockIdx.x * 4 + (threadIdx.x >> 6);
    const int lane = threadIdx.x & 63;
    const int e8 = lane >> 3;
    const int f8 = lane & 7;
    const char* hsb = (const char*)Hs;

    const int p0 = rowptr[node];
    const int p1 = rowptr[node + 1];

    float4 a0 = make_float4(0.f, 0.f, 0.f, 0.f);
    float4 a1 = make_float4(0.f, 0.f, 0.f, 0.f);
    int p = p0 + e8;
    for (; p + 8 < p1; p += 16) {
        const int2 c0 = csr[p];
        const int2 c1 = csr[p + 8];
        AGG_EDGE8(c0); AGG_EDGE8(c1);
    }
    if (p < p1) {
        const int2 c0 = csr[p];
        AGG_EDGE8(c0);
    }

#pragma unroll
    for (int m = 8; m < 64; m <<= 1) {
        a0.x += __shfl_xor(a0.x, m, 64);
        a0.y += __shfl_xor(a0.y, m, 64);
        a0.z += __shfl_xor(a0.z, m, 64);
        a0.w += __shfl_xor(a0.w, m, 64);
        a1.x += __shfl_xor(a1.x, m, 64);
        a1.y += __shfl_xor(a1.y, m, 64);
        a1.z += __shfl_xor(a1.z, m, 64);
        a1.w += __shfl_xor(a1.w, m, 64);
    }

    if (e8 == 0) {
        union { uint4 u; __half2 h2[4]; } hs;
        hs.u = *(const uint4*)(hsb + ((size_t)node << 7) + (f8 << 4));
        const float2 s0 = __half22float2(hs.h2[0]);
        const float2 s1 = __half22float2(hs.h2[1]);
        const float2 s2 = __half22float2(hs.h2[2]);
        const float2 s3 = __half22float2(hs.h2[3]);
        const float di = dinv[node];
        const float4 b0 = *(const float4*)&b[f8 << 3];
        const float4 b1 = *(const float4*)&b[(f8 << 3) + 4];
        union { uint4 u; __half2 h2[4]; } ov;
        ov.h2[0] = __floats2half2_rn(fmaxf(fmaf(di, a0.x + s0.x, b0.x), 0.f),
                                     fmaxf(fmaf(di, a0.y + s0.y, b0.y), 0.f));
        ov.h2[1] = __floats2half2_rn(fmaxf(fmaf(di, a0.z + s1.x, b0.z), 0.f),
                                     fmaxf(fmaf(di, a0.w + s1.y, b0.w), 0.f));
        ov.h2[2] = __floats2half2_rn(fmaxf(fmaf(di, a1.x + s2.x, b1.x), 0.f),
                                     fmaxf(fmaf(di, a1.y + s2.y, b1.y), 0.f));
        ov.h2[3] = __floats2half2_rn(fmaxf(fmaf(di, a1.z + s3.x, b1.z), 0.f),
                                     fmaxf(fmaf(di, a1.w + s3.y, b1.w), 0.f));
        *(uint4*)((char*)out + ((size_t)node << 7) + (f8 << 4)) = ov.u;
    }
}

// ------- fused readout: pooled = mean((A+B+C)/3) per graph; logits; softmax -------

__device__ __forceinline__ int lower_bound_i(const int* __restrict__ a, int n, int v) {
    int lo = 0, hi = n;
    while (lo < hi) {
        int mid = (lo + hi) >> 1;
        if (a[mid] < v) lo = mid + 1; else hi = mid;
    }
    return lo;
}

__global__ __launch_bounds__(256) void k_pool3_head(const __half* __restrict__ A,
                                                    const __half* __restrict__ B,
                                                    const __half* __restrict__ C,
                                                    const int* __restrict__ batch,
                                                    const float* __restrict__ Wl,
                                                    const float* __restrict__ bl,
                                                    float* __restrict__ out, int n) {
    const int g = blockIdx.x;
    const int tid = threadIdx.x;
    const int start = lower_bound_i(batch, n, g);
    const int end = lower_bound_i(batch, n, g + 1);

    const int fq = tid & 15;
    const int q = tid >> 4;
    float4 s = make_float4(0.f, 0.f, 0.f, 0.f);
    for (int nn = start + q; nn < end; nn += 16) {
        const size_t base = (size_t)nn * 64 + fq * 4;
        union { uint2 u; __half2 h2[2]; } va, vb, vc;
        va.u = *(const uint2*)&A[base];
        vb.u = *(const uint2*)&B[base];
        vc.u = *(const uint2*)&C[base];
        const float2 a0 = __half22float2(va.h2[0]);
        const float2 a1 = __half22float2(va.h2[1]);
        const float2 b0 = __half22float2(vb.h2[0]);
        const float2 b1 = __half22float2(vb.h2[1]);
        const float2 c0 = __half22float2(vc.h2[0]);
        const float2 c1 = __half22float2(vc.h2[1]);
        s.x += a0.x + b0.x + c0.x;
        s.y += a0.y + b0.y + c0.y;
        s.z += a1.x + b1.x + c1.x;
        s.w += a1.y + b1.y + c1.y;
    }
    __shared__ float4 red[16][16];
    red[q][fq] = s;
    __syncthreads();
    for (int off = 8; off > 0; off >>= 1) {
        if (q < off) {
            float4 a = red[q][fq];
            const float4 bb = red[q + off][fq];
            a.x += bb.x; a.y += bb.y; a.z += bb.z; a.w += bb.w;
            red[q][fq] = a;
        }
        __syncthreads();
    }
    __shared__ float pool[64];
    __shared__ float logits[10];
    if (tid < 16) {
        const float4 t = red[0][fq];
        pool[fq * 4 + 0] = t.x;
        pool[fq * 4 + 1] = t.y;
        pool[fq * 4 + 2] = t.z;
        pool[fq * 4 + 3] = t.w;
    }
    __syncthreads();
    const int cnt = end - start;
    const float scale = 1.0f / (3.0f * (float)(cnt < 1 ? 1 : cnt));
    if (tid < 10) {
        float acc = bl[tid];
        for (int k = 0; k < 64; ++k) {
            acc = fmaf(pool[k] * scale, Wl[k * 10 + tid], acc);
        }
        logits[tid] = acc;
    }
    __syncthreads();
    if (tid == 0) {
        float m = logits[0];
#pragma unroll
        for (int j = 1; j < 10; ++j) m = fmaxf(m, logits[j]);
        float sum = 0.f;
        float ex[10];
#pragma unroll
        for (int j = 0; j < 10; ++j) { ex[j] = expf(logits[j] - m); sum += ex[j]; }
        const float inv = 1.f / sum;
#pragma unroll
        for (int j = 0; j < 10; ++j) out[g * 10 + j] = ex[j] * inv;
    }
}

// ---------------- launcher ----------------

static inline size_t align256(size_t x) { return (x + 255) & ~(size_t)255; }

extern "C" void kernel_launch(void* const* d_in, const int* in_sizes, int n_in,
                              void* d_out, int out_size, void* d_ws, size_t ws_size,
                              hipStream_t stream) {
    const float* x  = (const float*)d_in[0];
    const float* ew = (const float*)d_in[1];
    const float* W1 = (const float*)d_in[2];
    const float* b1 = (const float*)d_in[3];
    const float* W2 = (const float*)d_in[4];
    const float* b2 = (const float*)d_in[5];
    const float* W3 = (const float*)d_in[6];
    const float* b3 = (const float*)d_in[7];
    const float* Wl = (const float*)d_in[8];
    const float* bl = (const float*)d_in[9];
    const int* eidx  = (const int*)d_in[10];
    const int* batch = (const int*)d_in[11];
    const int* src = eidx;
    const int* dst = eidx + N_EDGES;

    // workspace layout — every region 256B-aligned (Hs row gathers need 128B alignment!)
    char* base = (char*)d_ws;
    size_t off = 0;
    float* dinv   = (float*)(base + off); off = align256(off + N_NODES * 4);
    int* rowptr   = (int*)(base + off);   off = align256(off + (N_NODES + 1) * 4);
    int* Hist     = (int*)(base + off);   off = align256(off + HIST_N * 4);
    int* bsum     = (int*)(base + off);   off = align256(off + 640 * 4);
    int2* part    = (int2*)(base + off);  off = align256(off + (size_t)N_EDGES * 8);
    int2* csr     = (int2*)(base + off);  off = align256(off + (size_t)N_EDGES * 8);
    __half* Hs    = (__half*)(base + off); off = align256(off + (size_t)64 * N_NODES * 2);
    __half* A     = (__half*)(base + off); off = align256(off + (size_t)64 * N_NODES * 2);
    __half* B     = (__half*)(base + off); off = align256(off + (size_t)64 * N_NODES * 2);
    __half* C     = (__half*)(base + off); off = align256(off + (size_t)64 * N_NODES * 2);

    float* outf = (float*)d_out;

    // ---- atomic-free CSR build (counting sort, unpadded R13 form) ----
    k_hist<<<NBLK_P, 256, 0, stream>>>(dst, Hist, N_EDGES);
    k_scan_local<<<SCAN_NB, 256, 0, stream>>>(Hist, Hist, bsum, HIST_N);
    k_scan_bsum_par<<<1, 256, 0, stream>>>(bsum, SCAN_NB);
    k_partition<<<NBLK_P, 256, 0, stream>>>(src, dst, ew, Hist, bsum, part, N_EDGES);
    k_bucket_csr<<<NB_BUCKETS, 256, 0, stream>>>(part, Hist, bsum, csr, rowptr, dinv,
                                                 N_EDGES, N_NODES);

    const int nagg = N_NODES / 4;              // 25000 blocks, 1 wave per node
    const int ngemm = (N_NODES + 63) / 64;     // 1563 blocks

    // layer 1
    k_gemm_mfma<128, true><<<ngemm, 256, 0, stream>>>(x, W1, dinv, Hs, N_NODES);
    k_agg<<<nagg, 256, 0, stream>>>(Hs, rowptr, csr, dinv, b1, A);
    // layer 2
    k_gemm_mfma<64, false><<<ngemm, 256, 0, stream>>>(A, W2, dinv, Hs, N_NODES);
    k_agg<<<nagg, 256, 0, stream>>>(Hs, rowptr, csr, dinv, b2, B);
    // layer 3
    k_gemm_mfma<64, false><<<ngemm, 256, 0, stream>>>(B, W3, dinv, Hs, N_NODES);
    k_agg<<<nagg, 256, 0, stream>>>(Hs, rowptr, csr, dinv, b3, C);

    // fused readout (3-buffer pool + head + softmax)
    k_pool3_head<<<N_GRAPHS, 256, 0, stream>>>(A, B, C, batch, Wl, bl, outf, N_NODES);
}